// Round 13
// baseline (196.879 us; speedup 1.0000x reference)
//
#include <hip/hip_runtime.h>

#define KLAB 32
#define FDIM 32
#define NPIX (512 * 512)
#define BATCH 8
#define EPSF 1e-12f

typedef __attribute__((ext_vector_type(8))) short bf16x8;
typedef __attribute__((ext_vector_type(4))) short bf16x4;
typedef __attribute__((ext_vector_type(4))) float f32x4;

__device__ __forceinline__ short f2bf(float f) {
    unsigned u = __builtin_bit_cast(unsigned, f);
    unsigned r = (u + 0x7FFFu + ((u >> 16) & 1u)) >> 16;   // RNE
    return (short)r;
}

__device__ __forceinline__ float bf2f(short s) {
    return __builtin_bit_cast(float, (unsigned)((unsigned short)s) << 16);
}

// Pass 0: pure streaming fp32->bf16 convert + label byte-pack.
// Copy-regime kernel (load->cvt->store, no compute waits): TLP hides all
// latency; mixed R+W streams run ~6.3 TB/s (m13 D2D copy evidence).
__global__ __launch_bounds__(256) void k_cvt(
    const float* __restrict__ x, const int* __restrict__ lab,
    short* __restrict__ xbf, unsigned char* __restrict__ labp)
{
    const int tid = blockIdx.x * 256 + threadIdx.x;
    const int nthr = gridDim.x * 256;               // 524288
    const int nx8 = BATCH * FDIM * NPIX / 8;        // 8M chunks of 8 floats
    for (int i = tid; i < nx8; i += nthr) {
        const size_t o = (size_t)i * 8;
        const f32x4 v0 = *reinterpret_cast<const f32x4*>(&x[o]);
        const f32x4 v1 = *reinterpret_cast<const f32x4*>(&x[o + 4]);
        bf16x8 c;
        c[0]=f2bf(v0.x); c[1]=f2bf(v0.y); c[2]=f2bf(v0.z); c[3]=f2bf(v0.w);
        c[4]=f2bf(v1.x); c[5]=f2bf(v1.y); c[6]=f2bf(v1.z); c[7]=f2bf(v1.w);
        *reinterpret_cast<bf16x8*>(&xbf[o]) = c;
    }
    const int nl4 = BATCH * NPIX / 4;               // 2M chunks of 4 labels
    for (int i = tid; i < nl4; i += nthr) {
        const int4 l4 = *reinterpret_cast<const int4*>(&lab[(size_t)i * 4]);
        const unsigned p = (unsigned)(l4.x & 255) | ((unsigned)(l4.y & 255) << 8) |
                           ((unsigned)(l4.z & 255) << 16) | ((unsigned)(l4.w & 255) << 24);
        *reinterpret_cast<unsigned*>(&labp[(size_t)i * 4]) = p;
    }
}

// Pass 1: MFMA one-hot GEMM from the bf16 copy + packed labels.
// Per 32-px step: 2x16B x-loads + 1x8B label load, zero conversion VALU.
// Depth-4 slot rotation, fully unrolled (static slots), sched_barrier(0)
// pins load issue so hipcc can't sink them (round-9 failure mode).
__global__ __launch_bounds__(256) void k_msums(
    const short* __restrict__ xbf, const unsigned char* __restrict__ labp,
    float* __restrict__ g_sums, float* __restrict__ g_cnt)
{
    const int tid = threadIdx.x;
    const int b = blockIdx.y;
    const int w = tid >> 6, l = tid & 63;
    const int row = l & 15, grp = l >> 4;
    const int gw = blockIdx.x * 4 + w;              // 0..1023 waves per batch
    const size_t xb = (size_t)b * FDIM * NPIX;
    const size_t lb = (size_t)b * NPIX;

    f32x4 acc00{}, acc01{}, acc10{}, acc11{}, accC0{}, accC1{};
    bf16x8 ones;
#pragma unroll
    for (int j = 0; j < 8; ++j) ones[j] = (short)0x3F80;

    const short* xr0 = xbf + xb + (size_t)row * NPIX;
    const short* xr1 = xbf + xb + (size_t)(row + 16) * NPIX;

    bf16x8 sa0[4], sa1[4];
    unsigned long long slb[4];

#define LOADG(s, slot) do {                                                   \
    const int pg = (gw * 8 + (s)) * 32 + grp * 8;                             \
    sa0[slot] = *reinterpret_cast<const bf16x8*>(&xr0[pg]);                   \
    sa1[slot] = *reinterpret_cast<const bf16x8*>(&xr1[pg]);                   \
    slb[slot] = *reinterpret_cast<const unsigned long long*>(&labp[lb + pg]); \
    __builtin_amdgcn_sched_barrier(0); /* pin: loads may not sink below */    \
    } while (0)

    LOADG(0, 0); LOADG(1, 1); LOADG(2, 2); LOADG(3, 3);

#pragma unroll
    for (int s = 0; s < 8; ++s) {                   // full unroll: s&3 static
        const bf16x8 a0 = sa0[s & 3];
        const bf16x8 a1 = sa1[s & 3];
        const unsigned long long L = slb[s & 3];
        if (s + 4 < 8) LOADG(s + 4, s & 3);
        bf16x8 b0, b1;
#pragma unroll
        for (int j = 0; j < 8; ++j) {
            const int lj = (int)((L >> (8 * j)) & 0xFF);
            b0[j] = (lj == row)      ? (short)0x3F80 : (short)0;
            b1[j] = (lj == row + 16) ? (short)0x3F80 : (short)0;
        }
        acc00 = __builtin_amdgcn_mfma_f32_16x16x32_bf16(a0, b0, acc00, 0, 0, 0);
        acc10 = __builtin_amdgcn_mfma_f32_16x16x32_bf16(a1, b0, acc10, 0, 0, 0);
        acc01 = __builtin_amdgcn_mfma_f32_16x16x32_bf16(a0, b1, acc01, 0, 0, 0);
        acc11 = __builtin_amdgcn_mfma_f32_16x16x32_bf16(a1, b1, acc11, 0, 0, 0);
        accC0 = __builtin_amdgcn_mfma_f32_16x16x32_bf16(ones, b0, accC0, 0, 0, 0);
        accC1 = __builtin_amdgcn_mfma_f32_16x16x32_bf16(ones, b1, accC1, 0, 0, 0);
    }
#undef LOADG

    // Block-level LDS reduce of the 4 waves' [F][K] partials, then global atomics.
    __shared__ float s_red[4][FDIM * KLAB];
#pragma unroll
    for (int i = 0; i < 4; ++i) {
        // C layout: col = lane&15, row = (lane>>4)*4 + i  [measured m89]
        const int fr = grp * 4 + i;
        s_red[w][(fr)      * KLAB + row]      = acc00[i];
        s_red[w][(fr)      * KLAB + row + 16] = acc01[i];
        s_red[w][(fr + 16) * KLAB + row]      = acc10[i];
        s_red[w][(fr + 16) * KLAB + row + 16] = acc11[i];
    }
    __syncthreads();
    float* gs = g_sums + (size_t)b * FDIM * KLAB;
    for (int i = tid; i < FDIM * KLAB; i += 256)
        atomicAdd(&gs[i], s_red[0][i] + s_red[1][i] + s_red[2][i] + s_red[3][i]);
    if (l < 16) {   // counts: row 0 of ones-GEMM
        atomicAdd(&g_cnt[b * KLAB + l],      accC0[0]);
        atomicAdd(&g_cnt[b * KLAB + l + 16], accC1[0]);
    }
}

// Pass 2: per-pixel ||mu_label - x|| from the bf16 copy. 4 px/thread,
// depth-4 rotation fully unrolled. [proven ~20us @ 7.1 TB/s]
__global__ __launch_bounds__(256) void k_var(
    const short* __restrict__ xbf, const unsigned char* __restrict__ labp,
    const float* __restrict__ g_sums, const float* __restrict__ g_cnt,
    float* __restrict__ g_vsum)
{
    __shared__ float mu_s[FDIM][KLAB];
    __shared__ float vloc[KLAB];
    const int tid = threadIdx.x;
    const int b = blockIdx.y;
    for (int i = tid; i < FDIM * KLAB; i += 256) {
        const int k = i & (KLAB - 1);
        (&mu_s[0][0])[i] = g_sums[(size_t)b * FDIM * KLAB + i] / fmaxf(g_cnt[b * KLAB + k], 1.f);
    }
    if (tid < KLAB) vloc[tid] = 0.f;
    __syncthreads();

    const int n0 = blockIdx.x * 1024 + tid * 4;      // grid(256,B): 4 px/thread
    const size_t lb = (size_t)b * NPIX;
    const unsigned lp = *reinterpret_cast<const unsigned*>(&labp[lb + n0]);
    const int k0 = lp & 0xFF, k1 = (lp >> 8) & 0xFF, k2 = (lp >> 16) & 0xFF, k3 = lp >> 24;
    const short* xp = xbf + (size_t)b * FDIM * NPIX + n0;

    bf16x4 sl[4];
#pragma unroll
    for (int f = 0; f < 4; ++f)
        sl[f] = *reinterpret_cast<const bf16x4*>(xp + (size_t)f * NPIX);

    float d0 = 0.f, d1 = 0.f, d2 = 0.f, d3 = 0.f;
#pragma unroll
    for (int f = 0; f < FDIM; ++f) {                 // full unroll: f&3 static
        const bf16x4 cur = sl[f & 3];
        if (f + 4 < FDIM)
            sl[f & 3] = *reinterpret_cast<const bf16x4*>(xp + (size_t)(f + 4) * NPIX);
        const float* mf = &mu_s[f][0];
        float t;
        t = bf2f(cur[0]) - mf[k0]; d0 += t * t;
        t = bf2f(cur[1]) - mf[k1]; d1 += t * t;
        t = bf2f(cur[2]) - mf[k2]; d2 += t * t;
        t = bf2f(cur[3]) - mf[k3]; d3 += t * t;
    }
    float h;
    h = fmaxf(sqrtf(d0 + EPSF) - 0.5f, 0.f); atomicAdd(&vloc[k0], h * h);
    h = fmaxf(sqrtf(d1 + EPSF) - 0.5f, 0.f); atomicAdd(&vloc[k1], h * h);
    h = fmaxf(sqrtf(d2 + EPSF) - 0.5f, 0.f); atomicAdd(&vloc[k2], h * h);
    h = fmaxf(sqrtf(d3 + EPSF) - 0.5f, 0.f); atomicAdd(&vloc[k3], h * h);
    __syncthreads();
    if (tid < KLAB) atomicAdd(&g_vsum[b * KLAB + tid], vloc[tid]);
}

// Epilogue: all-batch mu staged once in LDS; wave-shuffle reductions; scalar out.
__global__ __launch_bounds__(256) void k_final(
    const float* __restrict__ g_sums, const float* __restrict__ g_cnt,
    const float* __restrict__ g_vsum, float* __restrict__ out)
{
    __shared__ float mu8[BATCH][FDIM][KLAB];   // 32 KB
    __shared__ float cnt8[BATCH][KLAB];
    __shared__ float tot[BATCH];
    const int tid = threadIdx.x;
    const int l = tid & 63, w = tid >> 6;

    for (int i = tid; i < BATCH * FDIM * KLAB; i += 256) {
        const int bb = i >> 10, k = i & 31;
        (&mu8[0][0][0])[i] = g_sums[i] / fmaxf(g_cnt[bb * KLAB + k], 1.f);
    }
    (&cnt8[0][0])[tid] = g_cnt[tid];           // 256 == BATCH*KLAB
    __syncthreads();

    for (int half = 0; half < 2; ++half) {
        const int bb = w + half * 4;           // wave w handles batches w, w+4
        float pres = 0.f, varp = 0.f, regp = 0.f, distp = 0.f;
        if (l < KLAB && cnt8[bb][l] > 0.f) {
            pres = 1.f;
            varp = g_vsum[bb * KLAB + l] / fmaxf(cnt8[bb][l], 1.f);
            float s = 0.f;
            for (int f = 0; f < FDIM; ++f) { float m = mu8[bb][f][l]; s += m * m; }
            regp = sqrtf(s + EPSF);
        }
        for (int p = l; p < KLAB * KLAB; p += 64) {
            const int i = p >> 5, j = p & 31;
            if (i < j && cnt8[bb][i] > 0.f && cnt8[bb][j] > 0.f) {
                float s = 0.f;
                for (int f = 0; f < FDIM; ++f) {
                    float d = mu8[bb][f][i] - mu8[bb][f][j]; s += d * d;
                }
                const float dist = sqrtf(s + EPSF);
                const float hg = fmaxf(1.5f - dist, 0.f);
                distp += hg * hg;
            }
        }
        for (int m = 32; m > 0; m >>= 1) {     // 64-lane butterfly
            pres  += __shfl_xor(pres,  m, 64);
            varp  += __shfl_xor(varp,  m, 64);
            regp  += __shfl_xor(regp,  m, 64);
            distp += __shfl_xor(distp, m, 64);
        }
        if (l == 0) {
            const float C = pres;
            const float var_b = (C > 0.f) ? varp / fmaxf(C, 1.f) : 0.f;
            const float dis_b = (C > 2.f) ? distp / fmaxf(C * (C - 1.f), 1.f) : 0.f;
            const float reg_b = (C > 1.f) ? regp : 0.f;
            tot[bb] = var_b + dis_b + 0.001f * reg_b;
        }
    }
    __syncthreads();
    if (tid == 0) {
        float t = 0.f;
        for (int bb = 0; bb < BATCH; ++bb) t += tot[bb];
        out[0] = t;
    }
}

extern "C" void kernel_launch(void* const* d_in, const int* in_sizes, int n_in,
                              void* d_out, int out_size, void* d_ws, size_t ws_size,
                              hipStream_t stream) {
    const float* x = (const float*)d_in[0];
    const int* lab = (const int*)d_in[1];
    float* out = (float*)d_out;

    // ws: xbf [B][F][N] bf16 (128 MiB) | labp [B][N] u8 (2 MiB) | sums | cnt | vsum
    const size_t XBF_BYTES = (size_t)BATCH * FDIM * NPIX * 2;
    const size_t LABP_BYTES = (size_t)BATCH * NPIX;
    short* xbf    = (short*)d_ws;
    unsigned char* labp = (unsigned char*)d_ws + XBF_BYTES;
    float* g_sums = (float*)((char*)d_ws + XBF_BYTES + LABP_BYTES);
    float* g_cnt  = g_sums + (size_t)BATCH * FDIM * KLAB;
    float* g_vsum = g_cnt + (size_t)BATCH * KLAB;
    hipMemsetAsync(g_sums, 0, (size_t)(BATCH * FDIM * KLAB + 2 * BATCH * KLAB) * 4, stream);

    k_cvt<<<2048, 256, 0, stream>>>(x, lab, xbf, labp);
    dim3 grid1(256, BATCH);    // 1024 waves/batch, 8 MFMA k-steps each
    k_msums<<<grid1, 256, 0, stream>>>(xbf, labp, g_sums, g_cnt);
    dim3 grid2(256, BATCH);    // 1024 px/block, 4 px/thread
    k_var<<<grid2, 256, 0, stream>>>(xbf, labp, g_sums, g_cnt, g_vsum);
    k_final<<<1, 256, 0, stream>>>(g_sums, g_cnt, g_vsum, out);
}

// Round 14
// 156.399 us; speedup vs baseline: 1.2588x; 1.2588x over previous
//
#include <hip/hip_runtime.h>

#define KLAB 32
#define FDIM 32
#define NPIX (512 * 512)
#define BATCH 8
#define EPSF 1e-12f

typedef __attribute__((ext_vector_type(8))) short bf16x8;
typedef __attribute__((ext_vector_type(4))) float f32x4;

__device__ __forceinline__ short f2bf(float f) {
    unsigned u = __builtin_bit_cast(unsigned, f);
    unsigned r = (u + 0x7FFFu + ((u >> 16) & 1u)) >> 16;   // RNE
    return (short)r;
}

// Pass 1: MFMA one-hot GEMM, direct global->register, NO stash.
// Depth-2 A/B rotation with sched_barrier(0) pinning load issue.
// [best measured stashless k_msums, round 12]
__global__ __launch_bounds__(256) void k_msums(
    const float* __restrict__ x, const int* __restrict__ lab,
    float* __restrict__ g_sums, float* __restrict__ g_cnt)
{
    const int tid = threadIdx.x;
    const int b = blockIdx.y;
    const int w = tid >> 6, l = tid & 63;
    const int row = l & 15, grp = l >> 4;
    const int gw = blockIdx.x * 4 + w;              // 0..1023 waves per batch
    const size_t xb = (size_t)b * FDIM * NPIX;
    const size_t lb = (size_t)b * NPIX;

    f32x4 acc00{}, acc01{}, acc10{}, acc11{}, accC0{}, accC1{};
    bf16x8 ones;
#pragma unroll
    for (int j = 0; j < 8; ++j) ones[j] = (short)0x3F80;

    const float* xr0 = x + xb + (size_t)row * NPIX;
    const float* xr1 = x + xb + (size_t)(row + 16) * NPIX;

#define LOADG(s, la, lc, v0, v1, v2, v3) do {                                 \
    const int pg = (gw * 8 + (s)) * 32 + grp * 8;                             \
    la = *reinterpret_cast<const int4*>(&lab[lb + pg]);                       \
    lc = *reinterpret_cast<const int4*>(&lab[lb + pg + 4]);                   \
    v0 = *reinterpret_cast<const f32x4*>(&xr0[pg]);                           \
    v1 = *reinterpret_cast<const f32x4*>(&xr0[pg + 4]);                       \
    v2 = *reinterpret_cast<const f32x4*>(&xr1[pg]);                           \
    v3 = *reinterpret_cast<const f32x4*>(&xr1[pg + 4]);                       \
    __builtin_amdgcn_sched_barrier(0); /* pin: loads may not sink below */    \
    } while (0)

#define COMPUTEG(la, lc, v0, v1, v2, v3) do {                                 \
    bf16x8 a0, a1, b0, b1;                                                    \
    a0[0]=f2bf(v0.x); a0[1]=f2bf(v0.y); a0[2]=f2bf(v0.z); a0[3]=f2bf(v0.w);   \
    a0[4]=f2bf(v1.x); a0[5]=f2bf(v1.y); a0[6]=f2bf(v1.z); a0[7]=f2bf(v1.w);   \
    a1[0]=f2bf(v2.x); a1[1]=f2bf(v2.y); a1[2]=f2bf(v2.z); a1[3]=f2bf(v2.w);   \
    a1[4]=f2bf(v3.x); a1[5]=f2bf(v3.y); a1[6]=f2bf(v3.z); a1[7]=f2bf(v3.w);   \
    const int lj[8] = {la.x, la.y, la.z, la.w, lc.x, lc.y, lc.z, lc.w};       \
    _Pragma("unroll")                                                         \
    for (int j = 0; j < 8; ++j) {                                             \
        b0[j] = (lj[j] == row)      ? (short)0x3F80 : (short)0;               \
        b1[j] = (lj[j] == row + 16) ? (short)0x3F80 : (short)0;               \
    }                                                                         \
    acc00 = __builtin_amdgcn_mfma_f32_16x16x32_bf16(a0, b0, acc00, 0, 0, 0);  \
    acc10 = __builtin_amdgcn_mfma_f32_16x16x32_bf16(a1, b0, acc10, 0, 0, 0);  \
    acc01 = __builtin_amdgcn_mfma_f32_16x16x32_bf16(a0, b1, acc01, 0, 0, 0);  \
    acc11 = __builtin_amdgcn_mfma_f32_16x16x32_bf16(a1, b1, acc11, 0, 0, 0);  \
    accC0 = __builtin_amdgcn_mfma_f32_16x16x32_bf16(ones, b0, accC0, 0, 0, 0);\
    accC1 = __builtin_amdgcn_mfma_f32_16x16x32_bf16(ones, b1, accC1, 0, 0, 0);\
    } while (0)

    int4 laA, lcA, laB, lcB;
    f32x4 vA0, vA1, vA2, vA3, vB0, vB1, vB2, vB3;

    LOADG(0, laA, lcA, vA0, vA1, vA2, vA3);
#pragma unroll
    for (int tt = 0; tt < 4; ++tt) {
        LOADG(2 * tt + 1, laB, lcB, vB0, vB1, vB2, vB3);
        COMPUTEG(laA, lcA, vA0, vA1, vA2, vA3);
        if (tt < 3) LOADG(2 * tt + 2, laA, lcA, vA0, vA1, vA2, vA3);
        COMPUTEG(laB, lcB, vB0, vB1, vB2, vB3);
    }
#undef LOADG
#undef COMPUTEG

    // Block-level LDS reduce of the 4 waves' [F][K] partials, then global atomics.
    __shared__ float s_red[4][FDIM * KLAB];
#pragma unroll
    for (int i = 0; i < 4; ++i) {
        // C layout: col = lane&15, row = (lane>>4)*4 + i  [measured m89]
        const int fr = grp * 4 + i;
        s_red[w][(fr)      * KLAB + row]      = acc00[i];
        s_red[w][(fr)      * KLAB + row + 16] = acc01[i];
        s_red[w][(fr + 16) * KLAB + row]      = acc10[i];
        s_red[w][(fr + 16) * KLAB + row + 16] = acc11[i];
    }
    __syncthreads();
    float* gs = g_sums + (size_t)b * FDIM * KLAB;
    for (int i = tid; i < FDIM * KLAB; i += 256)
        atomicAdd(&gs[i], s_red[0][i] + s_red[1][i] + s_red[2][i] + s_red[3][i]);
    if (l < 16) {   // counts: row 0 of ones-GEMM
        atomicAdd(&g_cnt[b * KLAB + l],      accC0[0]);
        atomicAdd(&g_cnt[b * KLAB + l + 16], accC1[0]);
    }
}

// Pass 2: per-pixel ||mu_label - x|| from fp32 x. 4 px/thread, DEPTH-8 slot
// rotation fully unrolled (128B/lane in flight; static f&7 indices), 8 blocks/CU.
__global__ __launch_bounds__(256) void k_var(
    const float* __restrict__ x, const int* __restrict__ lab,
    const float* __restrict__ g_sums, const float* __restrict__ g_cnt,
    float* __restrict__ g_vsum)
{
    __shared__ float mu_s[FDIM][KLAB];
    __shared__ float vloc[KLAB];
    const int tid = threadIdx.x;
    const int b = blockIdx.y;
    for (int i = tid; i < FDIM * KLAB; i += 256) {
        const int k = i & (KLAB - 1);
        (&mu_s[0][0])[i] = g_sums[(size_t)b * FDIM * KLAB + i] / fmaxf(g_cnt[b * KLAB + k], 1.f);
    }
    if (tid < KLAB) vloc[tid] = 0.f;
    __syncthreads();

    const int n0 = blockIdx.x * 1024 + tid * 4;      // grid(256,B): 4 px/thread
    const size_t lb = (size_t)b * NPIX;
    const int4 l4 = *reinterpret_cast<const int4*>(&lab[lb + n0]);
    const int k0 = l4.x & 31, k1 = l4.y & 31, k2 = l4.z & 31, k3 = l4.w & 31;
    const float* xp = x + (size_t)b * FDIM * NPIX + n0;

    f32x4 sl[8];
#pragma unroll
    for (int f = 0; f < 8; ++f)
        sl[f] = *reinterpret_cast<const f32x4*>(xp + (size_t)f * NPIX);

    float d0 = 0.f, d1 = 0.f, d2 = 0.f, d3 = 0.f;
#pragma unroll
    for (int f = 0; f < FDIM; ++f) {                 // full unroll: f&7 static
        const f32x4 cur = sl[f & 7];
        if (f + 8 < FDIM)
            sl[f & 7] = *reinterpret_cast<const f32x4*>(xp + (size_t)(f + 8) * NPIX);
        const float* mf = &mu_s[f][0];
        float t;
        t = cur.x - mf[k0]; d0 += t * t;
        t = cur.y - mf[k1]; d1 += t * t;
        t = cur.z - mf[k2]; d2 += t * t;
        t = cur.w - mf[k3]; d3 += t * t;
    }
    float h;
    h = fmaxf(sqrtf(d0 + EPSF) - 0.5f, 0.f); atomicAdd(&vloc[k0], h * h);
    h = fmaxf(sqrtf(d1 + EPSF) - 0.5f, 0.f); atomicAdd(&vloc[k1], h * h);
    h = fmaxf(sqrtf(d2 + EPSF) - 0.5f, 0.f); atomicAdd(&vloc[k2], h * h);
    h = fmaxf(sqrtf(d3 + EPSF) - 0.5f, 0.f); atomicAdd(&vloc[k3], h * h);
    __syncthreads();
    if (tid < KLAB) atomicAdd(&g_vsum[b * KLAB + tid], vloc[tid]);
}

// Epilogue: all-batch mu staged once in LDS; wave-shuffle reductions; scalar out.
__global__ __launch_bounds__(256) void k_final(
    const float* __restrict__ g_sums, const float* __restrict__ g_cnt,
    const float* __restrict__ g_vsum, float* __restrict__ out)
{
    __shared__ float mu8[BATCH][FDIM][KLAB];   // 32 KB
    __shared__ float cnt8[BATCH][KLAB];
    __shared__ float tot[BATCH];
    const int tid = threadIdx.x;
    const int l = tid & 63, w = tid >> 6;

    for (int i = tid; i < BATCH * FDIM * KLAB; i += 256) {
        const int bb = i >> 10, k = i & 31;
        (&mu8[0][0][0])[i] = g_sums[i] / fmaxf(g_cnt[bb * KLAB + k], 1.f);
    }
    (&cnt8[0][0])[tid] = g_cnt[tid];           // 256 == BATCH*KLAB
    __syncthreads();

    for (int half = 0; half < 2; ++half) {
        const int bb = w + half * 4;           // wave w handles batches w, w+4
        float pres = 0.f, varp = 0.f, regp = 0.f, distp = 0.f;
        if (l < KLAB && cnt8[bb][l] > 0.f) {
            pres = 1.f;
            varp = g_vsum[bb * KLAB + l] / fmaxf(cnt8[bb][l], 1.f);
            float s = 0.f;
            for (int f = 0; f < FDIM; ++f) { float m = mu8[bb][f][l]; s += m * m; }
            regp = sqrtf(s + EPSF);
        }
        for (int p = l; p < KLAB * KLAB; p += 64) {
            const int i = p >> 5, j = p & 31;
            if (i < j && cnt8[bb][i] > 0.f && cnt8[bb][j] > 0.f) {
                float s = 0.f;
                for (int f = 0; f < FDIM; ++f) {
                    float d = mu8[bb][f][i] - mu8[bb][f][j]; s += d * d;
                }
                const float dist = sqrtf(s + EPSF);
                const float hg = fmaxf(1.5f - dist, 0.f);
                distp += hg * hg;
            }
        }
        for (int m = 32; m > 0; m >>= 1) {     // 64-lane butterfly
            pres  += __shfl_xor(pres,  m, 64);
            varp  += __shfl_xor(varp,  m, 64);
            regp  += __shfl_xor(regp,  m, 64);
            distp += __shfl_xor(distp, m, 64);
        }
        if (l == 0) {
            const float C = pres;
            const float var_b = (C > 0.f) ? varp / fmaxf(C, 1.f) : 0.f;
            const float dis_b = (C > 2.f) ? distp / fmaxf(C * (C - 1.f), 1.f) : 0.f;
            const float reg_b = (C > 1.f) ? regp : 0.f;
            tot[bb] = var_b + dis_b + 0.001f * reg_b;
        }
    }
    __syncthreads();
    if (tid == 0) {
        float t = 0.f;
        for (int bb = 0; bb < BATCH; ++bb) t += tot[bb];
        out[0] = t;
    }
}

extern "C" void kernel_launch(void* const* d_in, const int* in_sizes, int n_in,
                              void* d_out, int out_size, void* d_ws, size_t ws_size,
                              hipStream_t stream) {
    const float* x = (const float*)d_in[0];
    const int* lab = (const int*)d_in[1];
    float* out = (float*)d_out;

    // ws: sums [B][F][K] | counts [B][K] | vsums [B][K]  (all float)
    float* g_sums = (float*)d_ws;
    float* g_cnt  = g_sums + (size_t)BATCH * FDIM * KLAB;
    float* g_vsum = g_cnt + (size_t)BATCH * KLAB;
    hipMemsetAsync(d_ws, 0, (size_t)(BATCH * FDIM * KLAB + 2 * BATCH * KLAB) * 4, stream);

    dim3 grid1(256, BATCH);    // 1024 waves/batch, 8 MFMA k-steps each
    k_msums<<<grid1, 256, 0, stream>>>(x, lab, g_sums, g_cnt);
    dim3 grid2(256, BATCH);    // 1024 px/block, 4 px/thread, 8 blocks/CU
    k_var<<<grid2, 256, 0, stream>>>(x, lab, g_sums, g_cnt, g_vsum);
    k_final<<<1, 256, 0, stream>>>(g_sums, g_cnt, g_vsum, out);
}

// Round 15
// 149.785 us; speedup vs baseline: 1.3144x; 1.0442x over previous
//
#include <hip/hip_runtime.h>

#define KLAB 32
#define FDIM 32
#define NPIX (512 * 512)
#define BATCH 8
#define EPSF 1e-12f

typedef __attribute__((ext_vector_type(8))) short bf16x8;
typedef __attribute__((ext_vector_type(4))) short bf16x4;
typedef __attribute__((ext_vector_type(4))) float f32x4;

__device__ __forceinline__ short f2bf(float f) {
    unsigned u = __builtin_bit_cast(unsigned, f);
    unsigned r = (u + 0x7FFFu + ((u >> 16) & 1u)) >> 16;   // RNE
    return (short)r;
}

__device__ __forceinline__ float bf2f(short s) {
    return __builtin_bit_cast(float, (unsigned)((unsigned short)s) << 16);
}

// Raw barrier: drain LDS ops only; global loads/stores stay in flight.
// (A __syncthreads would emit s_waitcnt vmcnt(0) and destroy the prefetch.)
#define LBARRIER() do {                                                \
    __builtin_amdgcn_sched_barrier(0);                                 \
    asm volatile("s_waitcnt lgkmcnt(0)\n\ts_barrier" ::: "memory");    \
    __builtin_amdgcn_sched_barrier(0);                                 \
} while (0)

// Pass 1: LDS-staged MFMA one-hot GEMM (contiguous 1KB/instr staging loads),
// bf16 stash for pass 2, double-buffered swizzled LDS, and a 2-tile-ahead
// register prefetch that SURVIVES barriers because LBARRIER drains only DS.
__global__ __launch_bounds__(256) void k_msums(
    const float* __restrict__ x, const int* __restrict__ lab,
    float* __restrict__ g_sums, float* __restrict__ g_cnt,
    short* __restrict__ xbf)
{
    __shared__ __align__(16) short alds[2][32 * 256];   // 2 x 16 KB bf16 tile
    __shared__ int lablds[2][256];

    const int tid = threadIdx.x;
    const int b = blockIdx.y;
    const int cx = blockIdx.x;                 // 0..127
    const int w = tid >> 6, l = tid & 63;      // 4 waves
    const int row = l & 15, grp = l >> 4;
    const int l4i = l * 4;
    const size_t xb = (size_t)b * FDIM * NPIX;
    const size_t lb = (size_t)b * NPIX;
    const int bp0 = cx * 2048;                 // 8 tiles x 256 px

    const float* xw = x + xb + (size_t)(w * 8) * NPIX;   // wave's 8 staging rows
    short* xbw = xbf + xb + (size_t)(w * 8) * NPIX;

    f32x4 acc00{}, acc01{}, acc10{}, acc11{}, accC0{}, accC1{};
    bf16x8 ones;
#pragma unroll
    for (int j = 0; j < 8; ++j) ones[j] = (short)0x3F80;

    f32x4 svA[8], svB[8];
    int slabA, slabB;

#define ISSUE(sp, sv, slab) do {                                              \
    _Pragma("unroll")                                                         \
    for (int r = 0; r < 8; ++r)                                               \
        sv[r] = *reinterpret_cast<const f32x4*>(                              \
            xw + (size_t)r * NPIX + (sp) + l4i);                              \
    slab = lab[lb + (sp) + tid];                                              \
    __builtin_amdgcn_sched_barrier(0); /* pin: loads may not sink */          \
} while (0)

#define WRITE(bufi, sp, sv, slab) do {                                        \
    _Pragma("unroll")                                                         \
    for (int r = 0; r < 8; ++r) {                                             \
        const f32x4 v = sv[r];                                                \
        bf16x4 c;                                                             \
        c[0]=f2bf(v.x); c[1]=f2bf(v.y); c[2]=f2bf(v.z); c[3]=f2bf(v.w);       \
        *reinterpret_cast<bf16x4*>(xbw + (size_t)r * NPIX + (sp) + l4i) = c;  \
        *reinterpret_cast<bf16x4*>((char*)&alds[bufi][0] +                    \
            (((w * 8 + r) * 512 + l * 8) ^ (r << 4))) = c;                    \
    }                                                                         \
    lablds[bufi][tid] = slab;                                                 \
} while (0)

#define COMPUTE(bufi) do {                                                    \
    _Pragma("unroll")                                                         \
    for (int kq = 0; kq < 2; ++kq) {                                          \
        const int kk = 2 * w + kq;                                            \
        const int cbyte = (kk * 32 + grp * 8) * 2;                            \
        const int swz = (row & 7) << 4;                                       \
        const bf16x8 a0 = *reinterpret_cast<const bf16x8*>(                   \
            (char*)&alds[bufi][0] + ((row * 512 + cbyte) ^ swz));             \
        const bf16x8 a1 = *reinterpret_cast<const bf16x8*>(                   \
            (char*)&alds[bufi][0] + (((row + 16) * 512 + cbyte) ^ swz));      \
        const int base = kk * 32 + grp * 8;                                   \
        const int4 la = *reinterpret_cast<const int4*>(&lablds[bufi][base]);  \
        const int4 lc = *reinterpret_cast<const int4*>(&lablds[bufi][base+4]);\
        bf16x8 b0, b1;                                                        \
        const int lj[8] = {la.x, la.y, la.z, la.w, lc.x, lc.y, lc.z, lc.w};   \
        _Pragma("unroll")                                                     \
        for (int j = 0; j < 8; ++j) {                                         \
            b0[j] = (lj[j] == row)      ? (short)0x3F80 : (short)0;           \
            b1[j] = (lj[j] == row + 16) ? (short)0x3F80 : (short)0;           \
        }                                                                     \
        acc00 = __builtin_amdgcn_mfma_f32_16x16x32_bf16(a0, b0, acc00, 0,0,0);\
        acc10 = __builtin_amdgcn_mfma_f32_16x16x32_bf16(a1, b0, acc10, 0,0,0);\
        acc01 = __builtin_amdgcn_mfma_f32_16x16x32_bf16(a0, b1, acc01, 0,0,0);\
        acc11 = __builtin_amdgcn_mfma_f32_16x16x32_bf16(a1, b1, acc11, 0,0,0);\
        accC0 = __builtin_amdgcn_mfma_f32_16x16x32_bf16(ones, b0, accC0,0,0,0);\
        accC1 = __builtin_amdgcn_mfma_f32_16x16x32_bf16(ones, b1, accC1,0,0,0);\
    }                                                                         \
} while (0)

    // prologue: T0->A, T1->B in flight; write T0 to buf0
    ISSUE(bp0, svA, slabA);
    ISSUE(bp0 + 256, svB, slabB);
    WRITE(0, bp0, svA, slabA);
    LBARRIER();

#pragma unroll 1
    for (int tt = 0; tt < 4; ++tt) {
        const int t0 = 2 * tt;
        // even tile t0: prefetch T(t0+2)->A; compute buf0; write T(t0+1) (B)->buf1
        if (t0 + 2 < 8) ISSUE(bp0 + (t0 + 2) * 256, svA, slabA);
        COMPUTE(0);
        WRITE(1, bp0 + (t0 + 1) * 256, svB, slabB);
        LBARRIER();
        // odd tile t0+1: prefetch T(t0+3)->B; compute buf1; write T(t0+2) (A)->buf0
        if (t0 + 3 < 8) ISSUE(bp0 + (t0 + 3) * 256, svB, slabB);
        COMPUTE(1);
        if (t0 + 2 < 8) WRITE(0, bp0 + (t0 + 2) * 256, svA, slabA);
        LBARRIER();
    }
#undef ISSUE
#undef WRITE
#undef COMPUTE

    // epilogue: block reduce (s_red aliases alds; all DS drained by LBARRIER)
    float* s_red = reinterpret_cast<float*>(&alds[0][0]);   // [4][1024]
#pragma unroll
    for (int i = 0; i < 4; ++i) {
        // C layout: col = lane&15, row = (lane>>4)*4 + i  [measured m89]
        const int fr = grp * 4 + i;
        s_red[w * 1024 + (fr)      * KLAB + row]      = acc00[i];
        s_red[w * 1024 + (fr)      * KLAB + row + 16] = acc01[i];
        s_red[w * 1024 + (fr + 16) * KLAB + row]      = acc10[i];
        s_red[w * 1024 + (fr + 16) * KLAB + row + 16] = acc11[i];
    }
    __syncthreads();
    float* gs = g_sums + (size_t)b * FDIM * KLAB;
    for (int i = tid; i < FDIM * KLAB; i += 256)
        atomicAdd(&gs[i], s_red[i] + s_red[1024 + i] + s_red[2048 + i] + s_red[3072 + i]);
    if (l < 16) {   // counts: row 0 of ones-GEMM
        atomicAdd(&g_cnt[b * KLAB + l],      accC0[0]);
        atomicAdd(&g_cnt[b * KLAB + l + 16], accC1[0]);
    }
}

// Pass 2: per-pixel ||mu_label - x|| from the bf16 stash. 4 px/thread,
// depth-4 rotation fully unrolled. [proven ~20 us @ 7.1 TB/s, round 7]
__global__ __launch_bounds__(256) void k_var(
    const short* __restrict__ xbf, const int* __restrict__ lab,
    const float* __restrict__ g_sums, const float* __restrict__ g_cnt,
    float* __restrict__ g_vsum)
{
    __shared__ float mu_s[FDIM][KLAB];
    __shared__ float vloc[KLAB];
    const int tid = threadIdx.x;
    const int b = blockIdx.y;
    for (int i = tid; i < FDIM * KLAB; i += 256) {
        const int k = i & (KLAB - 1);
        (&mu_s[0][0])[i] = g_sums[(size_t)b * FDIM * KLAB + i] / fmaxf(g_cnt[b * KLAB + k], 1.f);
    }
    if (tid < KLAB) vloc[tid] = 0.f;
    __syncthreads();

    const int n0 = blockIdx.x * 1024 + tid * 4;      // grid(256,B): 4 px/thread
    const size_t lb = (size_t)b * NPIX;
    const int4 l4 = *reinterpret_cast<const int4*>(&lab[lb + n0]);
    const int k0 = l4.x & 31, k1 = l4.y & 31, k2 = l4.z & 31, k3 = l4.w & 31;
    const short* xp = xbf + (size_t)b * FDIM * NPIX + n0;

    bf16x4 sl[4];
#pragma unroll
    for (int f = 0; f < 4; ++f)
        sl[f] = *reinterpret_cast<const bf16x4*>(xp + (size_t)f * NPIX);

    float d0 = 0.f, d1 = 0.f, d2 = 0.f, d3 = 0.f;
#pragma unroll
    for (int f = 0; f < FDIM; ++f) {                 // full unroll: f&3 static
        const bf16x4 cur = sl[f & 3];
        if (f + 4 < FDIM)
            sl[f & 3] = *reinterpret_cast<const bf16x4*>(xp + (size_t)(f + 4) * NPIX);
        const float* mf = &mu_s[f][0];
        float t;
        t = bf2f(cur[0]) - mf[k0]; d0 += t * t;
        t = bf2f(cur[1]) - mf[k1]; d1 += t * t;
        t = bf2f(cur[2]) - mf[k2]; d2 += t * t;
        t = bf2f(cur[3]) - mf[k3]; d3 += t * t;
    }
    float h;
    h = fmaxf(sqrtf(d0 + EPSF) - 0.5f, 0.f); atomicAdd(&vloc[k0], h * h);
    h = fmaxf(sqrtf(d1 + EPSF) - 0.5f, 0.f); atomicAdd(&vloc[k1], h * h);
    h = fmaxf(sqrtf(d2 + EPSF) - 0.5f, 0.f); atomicAdd(&vloc[k2], h * h);
    h = fmaxf(sqrtf(d3 + EPSF) - 0.5f, 0.f); atomicAdd(&vloc[k3], h * h);
    __syncthreads();
    if (tid < KLAB) atomicAdd(&g_vsum[b * KLAB + tid], vloc[tid]);
}

// Epilogue: all-batch mu staged once in LDS; wave-shuffle reductions; scalar out.
__global__ __launch_bounds__(256) void k_final(
    const float* __restrict__ g_sums, const float* __restrict__ g_cnt,
    const float* __restrict__ g_vsum, float* __restrict__ out)
{
    __shared__ float mu8[BATCH][FDIM][KLAB];   // 32 KB
    __shared__ float cnt8[BATCH][KLAB];
    __shared__ float tot[BATCH];
    const int tid = threadIdx.x;
    const int l = tid & 63, w = tid >> 6;

    for (int i = tid; i < BATCH * FDIM * KLAB; i += 256) {
        const int bb = i >> 10, k = i & 31;
        (&mu8[0][0][0])[i] = g_sums[i] / fmaxf(g_cnt[bb * KLAB + k], 1.f);
    }
    (&cnt8[0][0])[tid] = g_cnt[tid];           // 256 == BATCH*KLAB
    __syncthreads();

    for (int half = 0; half < 2; ++half) {
        const int bb = w + half * 4;           // wave w handles batches w, w+4
        float pres = 0.f, varp = 0.f, regp = 0.f, distp = 0.f;
        if (l < KLAB && cnt8[bb][l] > 0.f) {
            pres = 1.f;
            varp = g_vsum[bb * KLAB + l] / fmaxf(cnt8[bb][l], 1.f);
            float s = 0.f;
            for (int f = 0; f < FDIM; ++f) { float m = mu8[bb][f][l]; s += m * m; }
            regp = sqrtf(s + EPSF);
        }
        for (int p = l; p < KLAB * KLAB; p += 64) {
            const int i = p >> 5, j = p & 31;
            if (i < j && cnt8[bb][i] > 0.f && cnt8[bb][j] > 0.f) {
                float s = 0.f;
                for (int f = 0; f < FDIM; ++f) {
                    float d = mu8[bb][f][i] - mu8[bb][f][j]; s += d * d;
                }
                const float dist = sqrtf(s + EPSF);
                const float hg = fmaxf(1.5f - dist, 0.f);
                distp += hg * hg;
            }
        }
        for (int m = 32; m > 0; m >>= 1) {     // 64-lane butterfly
            pres  += __shfl_xor(pres,  m, 64);
            varp  += __shfl_xor(varp,  m, 64);
            regp  += __shfl_xor(regp,  m, 64);
            distp += __shfl_xor(distp, m, 64);
        }
        if (l == 0) {
            const float C = pres;
            const float var_b = (C > 0.f) ? varp / fmaxf(C, 1.f) : 0.f;
            const float dis_b = (C > 2.f) ? distp / fmaxf(C * (C - 1.f), 1.f) : 0.f;
            const float reg_b = (C > 1.f) ? regp : 0.f;
            tot[bb] = var_b + dis_b + 0.001f * reg_b;
        }
    }
    __syncthreads();
    if (tid == 0) {
        float t = 0.f;
        for (int bb = 0; bb < BATCH; ++bb) t += tot[bb];
        out[0] = t;
    }
}

extern "C" void kernel_launch(void* const* d_in, const int* in_sizes, int n_in,
                              void* d_out, int out_size, void* d_ws, size_t ws_size,
                              hipStream_t stream) {
    const float* x = (const float*)d_in[0];
    const int* lab = (const int*)d_in[1];
    float* out = (float*)d_out;

    // ws: xbf [B][F][N] bf16 (128 MiB) | sums [B][F][K] | counts [B][K] | vsums [B][K]
    const size_t XBF_BYTES = (size_t)BATCH * FDIM * NPIX * 2;
    short* xbf    = (short*)d_ws;
    float* g_sums = (float*)((char*)d_ws + XBF_BYTES);
    float* g_cnt  = g_sums + (size_t)BATCH * FDIM * KLAB;
    float* g_vsum = g_cnt + (size_t)BATCH * KLAB;
    hipMemsetAsync(g_sums, 0, (size_t)(BATCH * FDIM * KLAB + 2 * BATCH * KLAB) * 4, stream);

    dim3 grid1(128, BATCH);    // 1024 blocks, 4/CU co-resident
    k_msums<<<grid1, 256, 0, stream>>>(x, lab, g_sums, g_cnt, xbf);
    dim3 grid2(256, BATCH);    // 1024 px/block, 4 px/thread
    k_var<<<grid2, 256, 0, stream>>>(xbf, lab, g_sums, g_cnt, g_vsum);
    k_final<<<1, 256, 0, stream>>>(g_sums, g_cnt, g_vsum, out);
}